// Round 1
// baseline (33.849 us; speedup 1.0000x reference)
//
#include <hip/hip_runtime.h>
#include <hip/hip_bf16.h>
#include <math.h>

// L = 16x16 = 256 positions, D = 256, B = 32, N = 2.
// out[p,b,h] = silu( sum_{di<=i,dj<=j} K[h][di,dj] * x[(i-di,j-dj),b,h] + x[p,b,h]*omega[h] )
// K[h][cell] = C1[h,0]*GH0 + C1[h,1]*GH1 + C2[h,0]*GV0 + C2[h,1]*GV1, GH/GV = d-summed
// impulse responses of the coupled 2D recurrence (translation-invariant, causal).

__device__ __forceinline__ float sigh(float t) { return 0.5f / (1.0f + __expf(-t)); }

// k1: per-(d,n) 16x16 impulse responses -> W[cell*1024 + type*512 + n*256 + d]
__global__ void ssm_k1(const float* __restrict__ A1, const float* __restrict__ A2,
                       const float* __restrict__ A3, const float* __restrict__ A4,
                       const float* __restrict__ B1, const float* __restrict__ B2,
                       float* __restrict__ W) {
    int t = threadIdx.x;          // 512 threads
    int n = t >> 8, d = t & 255;
    int idx = d * 2 + n;
    float a1 = sigh(A1[idx]), a2 = sigh(A2[idx]);
    float a3 = sigh(A3[idx]), a4 = sigh(A4[idx]);
    float b1 = sigh(B1[idx]), b2 = sigh(B2[idx]);
    float ghp[16], gvp[16], gh[16], gv[16];
    #pragma unroll
    for (int di = 0; di < 16; ++di) {
        if (di == 0) {
            #pragma unroll
            for (int j = 0; j < 16; ++j) gv[j] = 0.f;
            gv[0] = b2;           // injection into x_v at the impulse cell
            gh[0] = b1;           // injection into x_h at the impulse cell
        } else {
            #pragma unroll
            for (int j = 0; j < 16; ++j) gv[j] = a3 * ghp[j] + a4 * gvp[j];
            gh[0] = 0.f;          // inner scan starts from zero carry
        }
        #pragma unroll
        for (int j = 1; j < 16; ++j) gh[j] = a1 * gh[j-1] + a2 * gv[j-1];
        #pragma unroll
        for (int j = 0; j < 16; ++j) {
            int cell = di * 16 + j;
            W[cell * 1024 +       n * 256 + d] = gh[j];
            W[cell * 1024 + 512 + n * 256 + d] = gv[j];
        }
        #pragma unroll
        for (int j = 0; j < 16; ++j) { ghp[j] = gh[j]; gvp[j] = gv[j]; }
    }
}

// k2: reduce W over d, combine with C1/C2 -> K[cell*256 + h] (h fastest)
__global__ void ssm_k2(const float* __restrict__ W, const float* __restrict__ C1,
                       const float* __restrict__ C2, float* __restrict__ Kk) {
    int cell = blockIdx.x;        // 256 blocks
    int t = threadIdx.x;          // 256 threads; t = d for the loads, t = h for the store
    float v0 = W[cell*1024 +        t];
    float v1 = W[cell*1024 + 256 +  t];
    float v2 = W[cell*1024 + 512 +  t];
    float v3 = W[cell*1024 + 768 +  t];
    #pragma unroll
    for (int m = 1; m < 64; m <<= 1) {
        v0 += __shfl_xor(v0, m);
        v1 += __shfl_xor(v1, m);
        v2 += __shfl_xor(v2, m);
        v3 += __shfl_xor(v3, m);
    }
    __shared__ float red[4][4];
    __shared__ float red2[4];
    int wid = t >> 6;
    if ((t & 63) == 0) { red[wid][0]=v0; red[wid][1]=v1; red[wid][2]=v2; red[wid][3]=v3; }
    __syncthreads();
    if (t < 4) red2[t] = red[0][t] + red[1][t] + red[2][t] + red[3][t];
    __syncthreads();
    float g0 = red2[0], g1 = red2[1], g2 = red2[2], g3 = red2[3];
    float c10 = C1[2*t], c11 = C1[2*t+1], c20 = C2[2*t], c21 = C2[2*t+1];
    Kk[cell*256 + t] = c10*g0 + c11*g1 + c20*g2 + c21*g3;
}

// k3: per-(b, h-tile) causal 2D conv + residual + silu
__global__ __launch_bounds__(256) void ssm_k3(const float* __restrict__ x,
                                              const float* __restrict__ Kk,
                                              const float* __restrict__ omega,
                                              float* __restrict__ out) {
    __shared__ float xs[256][32];   // [q][h_lane]
    __shared__ float ks[256][32];   // [cell][h_lane]
    int bx = blockIdx.x;            // 256 blocks = 32 b * 8 h-tiles
    int b  = bx >> 3;
    int h0 = (bx & 7) * 32;
    int t  = threadIdx.x;
    #pragma unroll
    for (int it = 0; it < 32; ++it) {
        int idx = it * 256 + t;
        int q = idx >> 5, hl = idx & 31;
        xs[q][hl] = x[(size_t)q * 8192 + b * 256 + h0 + hl];
        ks[q][hl] = Kk[q * 256 + h0 + hl];
    }
    __syncthreads();
    int hl = t & 31;
    int rslot = t >> 5;             // rows {rslot, 15-rslot}: 17*136 MACs/thread, balanced
    float om = omega[h0 + hl];
    #pragma unroll
    for (int rr = 0; rr < 2; ++rr) {
        int i = rr ? (15 - rslot) : rslot;
        float acc[16];
        #pragma unroll
        for (int j = 0; j < 16; ++j) acc[j] = 0.f;
        for (int di = 0; di <= i; ++di) {
            int srow = i - di;
            float kr[16];
            #pragma unroll
            for (int u = 0; u < 16; ++u) kr[u] = ks[di*16+u][hl];
            #pragma unroll
            for (int s = 0; s < 16; ++s) {
                float xv = xs[srow*16+s][hl];
                #pragma unroll
                for (int u = 0; u + s < 16; ++u) acc[s+u] += kr[u] * xv;
            }
        }
        #pragma unroll
        for (int j = 0; j < 16; ++j) {
            int p = i * 16 + j;
            float v = acc[j] + xs[p][hl] * om;
            out[(size_t)p * 8192 + b * 256 + h0 + hl] = v / (1.f + __expf(-v));
        }
    }
}

extern "C" void kernel_launch(void* const* d_in, const int* in_sizes, int n_in,
                              void* d_out, int out_size, void* d_ws, size_t ws_size,
                              hipStream_t stream) {
    const float* x  = (const float*)d_in[0];
    const float* A1 = (const float*)d_in[1];
    const float* A2 = (const float*)d_in[2];
    const float* A3 = (const float*)d_in[3];
    const float* A4 = (const float*)d_in[4];
    const float* B1 = (const float*)d_in[5];
    const float* B2 = (const float*)d_in[6];
    const float* C1 = (const float*)d_in[7];
    const float* C2 = (const float*)d_in[8];
    const float* omega = (const float*)d_in[9];
    float* out = (float*)d_out;
    float* W  = (float*)d_ws;            // 256*1024 floats = 1 MB
    float* Kk = W + 256 * 1024;          // 256*256 floats = 256 KB
    hipLaunchKernelGGL(ssm_k1, dim3(1),   dim3(512), 0, stream, A1, A2, A3, A4, B1, B2, W);
    hipLaunchKernelGGL(ssm_k2, dim3(256), dim3(256), 0, stream, W, C1, C2, Kk);
    hipLaunchKernelGGL(ssm_k3, dim3(256), dim3(256), 0, stream, x, Kk, omega, out);
}

// Round 2
// 32.199 us; speedup vs baseline: 1.0512x; 1.0512x over previous
//
#include <hip/hip_runtime.h>
#include <hip/hip_bf16.h>
#include <math.h>

// L = 16x16 = 256 positions, D = 256, B = 32, N = 2.
// out[p,b,h] = silu( sum_{di<=i,dj<=j} K[h][di,dj]*x[(i-di,j-dj),b,h] + x[p,b,h]*omega[h] )
// K[h][cell]  = C1[h,0]*GH0 + C1[h,1]*GH1 + C2[h,0]*GV0 + C2[h,1]*GV1
// GH_n/GV_n   = d-summed impulse responses of the coupled 2D recurrence
//               (translation-invariant + causal => only 16x16 taps per n).

__device__ __forceinline__ float sigh(float t) { return 0.5f / (1.0f + __expf(-t)); }

// kA: grid 2 (= n), block 256 (= d). Emits GHGV[(n*2+type)*256 + di*16 + j], 4 KB total.
__global__ __launch_bounds__(256) void ssm_kA(const float* __restrict__ A1, const float* __restrict__ A2,
                                              const float* __restrict__ A3, const float* __restrict__ A4,
                                              const float* __restrict__ B1, const float* __restrict__ B2,
                                              float* __restrict__ GHGV) {
    __shared__ float trr[256][36];   // [d][32 vals], padded to 36 for 16B-aligned rows
    __shared__ float part[32][8];    // [val][oct]
    int n = blockIdx.x, d = threadIdx.x;
    int idx = d * 2 + n;
    float a1 = sigh(A1[idx]), a2 = sigh(A2[idx]);
    float a3 = sigh(A3[idx]), a4 = sigh(A4[idx]);
    float b1 = sigh(B1[idx]), b2 = sigh(B2[idx]);
    float ghp[16], gvp[16], gh[16], gv[16], acc[16];
    int v = d & 31, oct = d >> 5;
    for (int di = 0; di < 16; ++di) {
        if (di == 0) {
            #pragma unroll
            for (int j = 0; j < 16; ++j) gv[j] = 0.f;
            gv[0] = b2;               // injection into x_v at the impulse cell
            gh[0] = b1;               // injection into x_h at the impulse cell
        } else {
            #pragma unroll
            for (int j = 0; j < 16; ++j) gv[j] = a3 * ghp[j] + a4 * gvp[j];
            gh[0] = 0.f;
        }
        #pragma unroll
        for (int j = 1; j < 16; ++j) gh[j] = a1 * gh[j-1] + a2 * gv[j-1];
        // stage this row's 32 values, transpose-reduce over d
        float4* wp = (float4*)&trr[d][0];
        wp[0] = make_float4(gh[0],  gh[1],  gh[2],  gh[3]);
        wp[1] = make_float4(gh[4],  gh[5],  gh[6],  gh[7]);
        wp[2] = make_float4(gh[8],  gh[9],  gh[10], gh[11]);
        wp[3] = make_float4(gh[12], gh[13], gh[14], gh[15]);
        wp[4] = make_float4(gv[0],  gv[1],  gv[2],  gv[3]);
        wp[5] = make_float4(gv[4],  gv[5],  gv[6],  gv[7]);
        wp[6] = make_float4(gv[8],  gv[9],  gv[10], gv[11]);
        wp[7] = make_float4(gv[12], gv[13], gv[14], gv[15]);
        __syncthreads();
        float s = 0.f;
        #pragma unroll
        for (int i = 0; i < 32; ++i) s += trr[oct * 32 + i][v];
        part[v][oct] = s;
        __syncthreads();
        float4 p0 = *(float4*)&part[v][0];
        float4 p1 = *(float4*)&part[v][4];
        acc[di] = (p0.x + p0.y + p0.z + p0.w) + (p1.x + p1.y + p1.z + p1.w);
        #pragma unroll
        for (int j = 0; j < 16; ++j) { ghp[j] = gh[j]; gvp[j] = gv[j]; }
    }
    if (oct == 0) {
        int type = v >> 4, j = v & 15;
        #pragma unroll
        for (int di = 0; di < 16; ++di)
            GHGV[(n * 2 + type) * 256 + di * 16 + j] = acc[di];
    }
}

// k3: per-(b, h-tile): fold C into K on the fly, then causal 2D conv + residual + silu
__global__ __launch_bounds__(256) void ssm_k3(const float* __restrict__ x,
                                              const float* __restrict__ GHGV,
                                              const float* __restrict__ C1,
                                              const float* __restrict__ C2,
                                              const float* __restrict__ omega,
                                              float* __restrict__ out) {
    __shared__ float xs[256][32];   // [q][h_lane]
    __shared__ float ks[256][32];   // [cell][h_lane]
    __shared__ float gs[1024];      // GHGV staged
    int bx = blockIdx.x;            // 256 blocks = 32 b * 8 h-tiles
    int b  = bx >> 3;
    int h0 = (bx & 7) * 32;
    int t  = threadIdx.x;
    gs[t]       = GHGV[t];
    gs[t + 256] = GHGV[t + 256];
    gs[t + 512] = GHGV[t + 512];
    gs[t + 768] = GHGV[t + 768];
    #pragma unroll
    for (int it = 0; it < 32; ++it) {
        int idx = it * 256 + t;
        int q = idx >> 5, hl = idx & 31;
        xs[q][hl] = x[(size_t)q * 8192 + b * 256 + h0 + hl];
    }
    __syncthreads();
    int hl = t & 31;
    int slot = t >> 5;
    int h = h0 + hl;
    float c10 = C1[2*h], c11 = C1[2*h+1], c20 = C2[2*h], c21 = C2[2*h+1];
    #pragma unroll
    for (int c = 0; c < 32; ++c) {
        int cell = slot * 32 + c;
        // GH0=gs[0..255], GV0=gs[256..511], GH1=gs[512..767], GV1=gs[768..1023]
        ks[cell][hl] = c10 * gs[cell] + c11 * gs[512 + cell]
                     + c20 * gs[256 + cell] + c21 * gs[768 + cell];
    }
    __syncthreads();
    int rslot = slot;               // rows {rslot, 15-rslot}: 17*136 MACs/thread, balanced
    float om = omega[h];
    #pragma unroll
    for (int rr = 0; rr < 2; ++rr) {
        int i = rr ? (15 - rslot) : rslot;
        float acc[16];
        #pragma unroll
        for (int j = 0; j < 16; ++j) acc[j] = 0.f;
        for (int di = 0; di <= i; ++di) {
            int srow = i - di;
            float kr[16];
            #pragma unroll
            for (int u = 0; u < 16; ++u) kr[u] = ks[di*16+u][hl];
            #pragma unroll
            for (int s = 0; s < 16; ++s) {
                float xv = xs[srow*16+s][hl];
                #pragma unroll
                for (int u = 0; u + s < 16; ++u) acc[s+u] += kr[u] * xv;
            }
        }
        #pragma unroll
        for (int j = 0; j < 16; ++j) {
            int p = i * 16 + j;
            float vv = acc[j] + xs[p][hl] * om;
            out[(size_t)p * 8192 + b * 256 + h0 + hl] = vv / (1.f + __expf(-vv));
        }
    }
}

extern "C" void kernel_launch(void* const* d_in, const int* in_sizes, int n_in,
                              void* d_out, int out_size, void* d_ws, size_t ws_size,
                              hipStream_t stream) {
    const float* x  = (const float*)d_in[0];
    const float* A1 = (const float*)d_in[1];
    const float* A2 = (const float*)d_in[2];
    const float* A3 = (const float*)d_in[3];
    const float* A4 = (const float*)d_in[4];
    const float* B1 = (const float*)d_in[5];
    const float* B2 = (const float*)d_in[6];
    const float* C1 = (const float*)d_in[7];
    const float* C2 = (const float*)d_in[8];
    const float* omega = (const float*)d_in[9];
    float* out  = (float*)d_out;
    float* GHGV = (float*)d_ws;          // 1024 floats = 4 KB
    hipLaunchKernelGGL(ssm_kA, dim3(2),   dim3(256), 0, stream,
                       A1, A2, A3, A4, B1, B2, GHGV);
    hipLaunchKernelGGL(ssm_k3, dim3(256), dim3(256), 0, stream,
                       x, GHGV, C1, C2, omega, out);
}

// Round 3
// 25.423 us; speedup vs baseline: 1.3314x; 1.2665x over previous
//
#include <hip/hip_runtime.h>
#include <hip/hip_bf16.h>
#include <math.h>

// L = 16x16 = 256 positions, D = 256, B = 32, N = 2.
// out[p,b,h] = silu( sum_{di<=i,dj<=j} K[h][di,dj]*x[(i-di,j-dj),b,h] + x[p,b,h]*omega[h] )
// K[h][cell] = C1[h,0]*GH0 + C1[h,1]*GH1 + C2[h,0]*GV0 + C2[h,1]*GV1
// GH_n/GV_n  = d-summed impulse responses (translation-invariant + causal => 16x16 taps).
// kP: 8 blocks x 64 thr compute PARTIAL d-sums (32 d's x 2 n each), k3 combines.

__device__ __forceinline__ float sigh(float t) { return 0.5f / (1.0f + __expf(-t)); }

// kP: grid 8 (d-groups), block 64 (32 d x 2 n). P[(g*4 + n*2 + type)*256 + di*16 + j]
__global__ __launch_bounds__(64) void ssm_kP(const float* __restrict__ A1, const float* __restrict__ A2,
                                             const float* __restrict__ A3, const float* __restrict__ A4,
                                             const float* __restrict__ B1, const float* __restrict__ B2,
                                             float* __restrict__ P) {
    __shared__ float buf[64][36];    // [thread][32 vals], pad->36 keeps b128 align + 2-way reads
    int g = blockIdx.x;
    int t = threadIdx.x;
    int dl = t & 31, n = t >> 5;
    int idx = (g * 32 + dl) * 2 + n;
    float a1 = sigh(A1[idx]), a2 = sigh(A2[idx]);
    float a3 = sigh(A3[idx]), a4 = sigh(A4[idx]);
    float b1 = sigh(B1[idx]), b2 = sigh(B2[idx]);
    float ghp[16], gvp[16], gh[16], gv[16], acc[16];
    int vL = t & 31, nR = t >> 5;    // reduce assignment: lane sums 32 rows of its n
    for (int di = 0; di < 16; ++di) {
        if (di == 0) {
            #pragma unroll
            for (int j = 0; j < 16; ++j) gv[j] = 0.f;
            gv[0] = b2;              // injection into x_v at the impulse cell
            gh[0] = b1;              // injection into x_h at the impulse cell
        } else {
            #pragma unroll
            for (int j = 0; j < 16; ++j) gv[j] = a3 * ghp[j] + a4 * gvp[j];
            gh[0] = 0.f;
        }
        #pragma unroll
        for (int j = 1; j < 16; ++j) gh[j] = a1 * gh[j-1] + a2 * gv[j-1];
        float4* wp = (float4*)&buf[t][0];
        wp[0] = make_float4(gh[0],  gh[1],  gh[2],  gh[3]);
        wp[1] = make_float4(gh[4],  gh[5],  gh[6],  gh[7]);
        wp[2] = make_float4(gh[8],  gh[9],  gh[10], gh[11]);
        wp[3] = make_float4(gh[12], gh[13], gh[14], gh[15]);
        wp[4] = make_float4(gv[0],  gv[1],  gv[2],  gv[3]);
        wp[5] = make_float4(gv[4],  gv[5],  gv[6],  gv[7]);
        wp[6] = make_float4(gv[8],  gv[9],  gv[10], gv[11]);
        wp[7] = make_float4(gv[12], gv[13], gv[14], gv[15]);
        __syncthreads();             // 1 wave: cheap
        float s = 0.f;
        #pragma unroll
        for (int i = 0; i < 32; ++i) s += buf[nR * 32 + i][vL];
        acc[di] = s;
        __syncthreads();             // WAR before next row's writes
        #pragma unroll
        for (int j = 0; j < 16; ++j) { ghp[j] = gh[j]; gvp[j] = gv[j]; }
    }
    int type = vL >> 4, j = vL & 15;
    int base = (g * 4 + nR * 2 + type) * 256 + j;
    #pragma unroll
    for (int di = 0; di < 16; ++di) P[base + di * 16] = acc[di];
}

// k3: per-(b, h-tile): combine partials -> GHGV, fold C -> K, causal 2D conv + silu
__global__ __launch_bounds__(256) void ssm_k3(const float* __restrict__ x,
                                              const float* __restrict__ P,
                                              const float* __restrict__ C1,
                                              const float* __restrict__ C2,
                                              const float* __restrict__ omega,
                                              float* __restrict__ out) {
    __shared__ float xs[256 * 32];   // [q][hl] flat, stride 32 (2-way reads = free)
    __shared__ float gsum[1024];     // combined GHGV
    __shared__ float ks[256][32];    // [cell][hl]
    int bx = blockIdx.x;             // 256 blocks = 32 b * 8 h-tiles
    int b  = bx >> 3;
    int h0 = (bx & 7) * 32;
    int t  = threadIdx.x;
    // 1) issue async x -> LDS first; latency hides under the combine prologue.
    //    LDS dest = idx*4 = wave-uniform base + lane*4 (required by global_load_lds).
    #pragma unroll
    for (int it = 0; it < 32; ++it) {
        int idx = it * 256 + t;
        int q = idx >> 5, hl = idx & 31;
        __builtin_amdgcn_global_load_lds(
            (const __attribute__((address_space(1))) void*)(x + (size_t)q * 8192 + b * 256 + h0 + hl),
            (__attribute__((address_space(3))) void*)(&xs[idx]), 4, 0, 0);
    }
    // 2) combine the 8 d-group partials (L2-hot broadcast): thread owns 4 cells
    {
        int o = t * 4;
        int pn = o >> 9, pt = (o >> 8) & 1, pc = o & 255;
        const float4* P4 = (const float4*)P;
        float4 a = make_float4(0.f, 0.f, 0.f, 0.f);
        #pragma unroll
        for (int g = 0; g < 8; ++g) {
            float4 v = P4[(g * 4 + pn * 2 + pt) * 64 + (pc >> 2)];
            a.x += v.x; a.y += v.y; a.z += v.z; a.w += v.w;
        }
        *(float4*)&gsum[o] = a;
    }
    __syncthreads();
    int hl = t & 31;
    int slot = t >> 5;
    int h = h0 + hl;
    float c10 = C1[2*h], c11 = C1[2*h+1], c20 = C2[2*h], c21 = C2[2*h+1];
    float om = omega[h];
    #pragma unroll
    for (int c = 0; c < 32; ++c) {
        int cell = slot * 32 + c;
        // GH0=gsum[0..255], GV0=gsum[256..511], GH1=gsum[512..767], GV1=gsum[768..1023]
        ks[cell][hl] = c10 * gsum[cell] + c11 * gsum[512 + cell]
                     + c20 * gsum[256 + cell] + c21 * gsum[768 + cell];
    }
    __syncthreads();                 // also drains the global_load_lds (vmcnt) for xs
    int rslot = slot;                // rows {rslot, 15-rslot}: 17*136 MACs/thread, balanced
    #pragma unroll
    for (int rr = 0; rr < 2; ++rr) {
        int i = rr ? (15 - rslot) : rslot;
        float acc[16];
        #pragma unroll
        for (int j = 0; j < 16; ++j) acc[j] = 0.f;
        for (int di = 0; di <= i; ++di) {
            int srow = i - di;
            float kr[16];
            #pragma unroll
            for (int u = 0; u < 16; ++u) kr[u] = ks[di*16+u][hl];
            #pragma unroll
            for (int s = 0; s < 16; ++s) {
                float xv = xs[(srow * 16 + s) * 32 + hl];
                #pragma unroll
                for (int u = 0; u + s < 16; ++u) acc[s+u] += kr[u] * xv;
            }
        }
        #pragma unroll
        for (int j = 0; j < 16; ++j) {
            int p = i * 16 + j;
            float vv = acc[j] + xs[p * 32 + hl] * om;
            out[(size_t)p * 8192 + b * 256 + h0 + hl] = vv / (1.f + __expf(-vv));
        }
    }
}

extern "C" void kernel_launch(void* const* d_in, const int* in_sizes, int n_in,
                              void* d_out, int out_size, void* d_ws, size_t ws_size,
                              hipStream_t stream) {
    const float* x  = (const float*)d_in[0];
    const float* A1 = (const float*)d_in[1];
    const float* A2 = (const float*)d_in[2];
    const float* A3 = (const float*)d_in[3];
    const float* A4 = (const float*)d_in[4];
    const float* B1 = (const float*)d_in[5];
    const float* B2 = (const float*)d_in[6];
    const float* C1 = (const float*)d_in[7];
    const float* C2 = (const float*)d_in[8];
    const float* omega = (const float*)d_in[9];
    float* out = (float*)d_out;
    float* P   = (float*)d_ws;           // 32*256 floats = 32 KB partial d-sums
    hipLaunchKernelGGL(ssm_kP, dim3(8),   dim3(64),  0, stream,
                       A1, A2, A3, A4, B1, B2, P);
    hipLaunchKernelGGL(ssm_k3, dim3(256), dim3(256), 0, stream,
                       x, P, C1, C2, omega, out);
}

// Round 4
// 24.279 us; speedup vs baseline: 1.3941x; 1.0471x over previous
//
#include <hip/hip_runtime.h>
#include <hip/hip_bf16.h>
#include <math.h>

// L = 16x16 = 256 positions, D = 256, B = 32, N = 2.
// out[p,b,h] = silu( sum_{di<=i,dj<=j} K[h][di,dj]*x[(i-di,j-dj),b,h] + x[p,b,h]*omega[h] )
// K[h][cell] = C1[h,0]*GH0 + C1[h,1]*GH1 + C2[h,0]*GV0 + C2[h,1]*GV1
// GH_n/GV_n  = d-summed impulse responses (translation-invariant + causal => 16x16 taps).
// kP: 8 blocks x 64 thr -> PARTIAL d-sums; k3: combine + causal 2D conv + silu.

__device__ __forceinline__ float sigh(float t) { return 0.5f / (1.0f + __expf(-t)); }

// kP: grid 8 (d-groups), block 64 (32 d x 2 n). P[(g*4 + n*2 + type)*256 + di*16 + j]
__global__ __launch_bounds__(64) void ssm_kP(const float* __restrict__ A1, const float* __restrict__ A2,
                                             const float* __restrict__ A3, const float* __restrict__ A4,
                                             const float* __restrict__ B1, const float* __restrict__ B2,
                                             float* __restrict__ P) {
    __shared__ float buf[64][36];    // [thread][32 vals], pad->36: conflict-free column reads
    int g = blockIdx.x;
    int t = threadIdx.x;
    int dl = t & 31, n = t >> 5;
    int idx = (g * 32 + dl) * 2 + n;
    float a1 = sigh(A1[idx]), a2 = sigh(A2[idx]);
    float a3 = sigh(A3[idx]), a4 = sigh(A4[idx]);
    float b1 = sigh(B1[idx]), b2 = sigh(B2[idx]);
    float gh[16], gv[16], acc[16];
    int vL = t & 31, nR = t >> 5;    // reduce role: lane vL sums 32 rows of its n
    // row 0
    #pragma unroll
    for (int j = 0; j < 16; ++j) gv[j] = 0.f;
    gv[0] = b2;                      // injection into x_v at the impulse cell
    gh[0] = b1;                      // injection into x_h at the impulse cell
    #pragma unroll
    for (int j = 1; j < 16; ++j) gh[j] = a1 * gh[j-1] + a2 * gv[j-1];
    for (int di = 0; di < 16; ++di) {
        float4* wp = (float4*)&buf[t][0];
        wp[0] = make_float4(gh[0],  gh[1],  gh[2],  gh[3]);
        wp[1] = make_float4(gh[4],  gh[5],  gh[6],  gh[7]);
        wp[2] = make_float4(gh[8],  gh[9],  gh[10], gh[11]);
        wp[3] = make_float4(gh[12], gh[13], gh[14], gh[15]);
        wp[4] = make_float4(gv[0],  gv[1],  gv[2],  gv[3]);
        wp[5] = make_float4(gv[4],  gv[5],  gv[6],  gv[7]);
        wp[6] = make_float4(gv[8],  gv[9],  gv[10], gv[11]);
        wp[7] = make_float4(gv[12], gv[13], gv[14], gv[15]);
        __syncthreads();
        // issue the 32 column reads first ...
        float v[32];
        #pragma unroll
        for (int i = 0; i < 32; ++i) v[i] = buf[nR * 32 + i][vL];
        // ... compute next row's recurrence while loads are in flight
        float ghn[16], gvn[16];
        if (di < 15) {
            #pragma unroll
            for (int j = 0; j < 16; ++j) gvn[j] = a3 * gh[j] + a4 * gv[j];
            ghn[0] = 0.f;
            #pragma unroll
            for (int j = 1; j < 16; ++j) ghn[j] = a1 * ghn[j-1] + a2 * gvn[j-1];
        }
        // tree-sum (depth 5, not a 32-deep serial chain)
        #pragma unroll
        for (int st = 16; st >= 1; st >>= 1)
            #pragma unroll
            for (int i = 0; i < st; ++i) v[i] += v[i + st];
        acc[di] = v[0];
        __syncthreads();             // WAR before next row's writes
        if (di < 15) {
            #pragma unroll
            for (int j = 0; j < 16; ++j) { gh[j] = ghn[j]; gv[j] = gvn[j]; }
        }
    }
    int type = vL >> 4, j = vL & 15;
    int base = (g * 4 + nR * 2 + type) * 256 + j;
    #pragma unroll
    for (int di = 0; di < 16; ++di) P[base + di * 16] = acc[di];
}

// k3: per-(b, h-tile): combine partials -> K (transposed in LDS), causal 2D conv + silu
__global__ __launch_bounds__(256) void ssm_k3(const float* __restrict__ x,
                                              const float* __restrict__ P,
                                              const float* __restrict__ C1,
                                              const float* __restrict__ C2,
                                              const float* __restrict__ omega,
                                              float* __restrict__ out) {
    __shared__ float xs[256 * 32];   // [q][hl] flat, stride 32 (2-way broadcast reads = free)
    __shared__ float gsum[1024];     // combined GHGV
    __shared__ float ks[32][260];    // [hl][cell], pad 260 -> odd 16B-group stride
    int bx = blockIdx.x;             // 256 blocks = 32 b * 8 h-tiles
    int b  = bx >> 3;
    int h0 = (bx & 7) * 32;
    int t  = threadIdx.x;
    // 1) async x -> LDS first; latency hides under the combine prologue.
    //    LDS dest = idx*4 = wave-uniform base + lane*4 (required by global_load_lds).
    #pragma unroll
    for (int it = 0; it < 32; ++it) {
        int idx = it * 256 + t;
        int q = idx >> 5, hl = idx & 31;
        __builtin_amdgcn_global_load_lds(
            (const __attribute__((address_space(1))) void*)(x + (size_t)q * 8192 + b * 256 + h0 + hl),
            (__attribute__((address_space(3))) void*)(&xs[idx]), 4, 0, 0);
    }
    // 2) combine the 8 d-group partials (L2-hot broadcast): thread owns 4 cells
    {
        int o = t * 4;
        int pn = o >> 9, pt = (o >> 8) & 1, pc = o & 255;
        const float4* P4 = (const float4*)P;
        float4 a = make_float4(0.f, 0.f, 0.f, 0.f);
        #pragma unroll
        for (int g = 0; g < 8; ++g) {
            float4 v = P4[(g * 4 + pn * 2 + pt) * 64 + (pc >> 2)];
            a.x += v.x; a.y += v.y; a.z += v.z; a.w += v.w;
        }
        *(float4*)&gsum[o] = a;
    }
    __syncthreads();
    int hl = t & 31;
    int slot = t >> 5;
    int h = h0 + hl;
    float c10 = C1[2*h], c11 = C1[2*h+1], c20 = C2[2*h], c21 = C2[2*h+1];
    float om = omega[h];
    // 3) fold C into K, store transposed: ks[hl][cell], float4 granularity
    #pragma unroll
    for (int cg = 0; cg < 8; ++cg) {
        int cell = slot * 32 + cg * 4;
        float4 gh0 = *(const float4*)&gsum[cell];
        float4 gv0 = *(const float4*)&gsum[256 + cell];
        float4 gh1 = *(const float4*)&gsum[512 + cell];
        float4 gv1 = *(const float4*)&gsum[768 + cell];
        float4 r;
        r.x = c10 * gh0.x + c11 * gh1.x + c20 * gv0.x + c21 * gv1.x;
        r.y = c10 * gh0.y + c11 * gh1.y + c20 * gv0.y + c21 * gv1.y;
        r.z = c10 * gh0.z + c11 * gh1.z + c20 * gv0.z + c21 * gv1.z;
        r.w = c10 * gh0.w + c11 * gh1.w + c20 * gv0.w + c21 * gv1.w;
        *(float4*)&ks[hl][cell] = r;
    }
    __syncthreads();                 // also drains global_load_lds (vmcnt) for xs
    int rslot = slot;                // rows {rslot, 15-rslot}: wave-balanced (~18 di-iters/wave)
    #pragma unroll
    for (int rr = 0; rr < 2; ++rr) {
        int i = rr ? (15 - rslot) : rslot;
        float acc[16];
        #pragma unroll
        for (int j = 0; j < 16; ++j) acc[j] = 0.f;
        for (int di = 0; di <= i; ++di) {
            int srow = i - di;
            float4 k0 = *(const float4*)&ks[hl][di * 16];
            float4 k1 = *(const float4*)&ks[hl][di * 16 + 4];
            float4 k2 = *(const float4*)&ks[hl][di * 16 + 8];
            float4 k3v = *(const float4*)&ks[hl][di * 16 + 12];
            float kr[16] = {k0.x, k0.y, k0.z, k0.w, k1.x, k1.y, k1.z, k1.w,
                            k2.x, k2.y, k2.z, k2.w, k3v.x, k3v.y, k3v.z, k3v.w};
            #pragma unroll
            for (int s = 0; s < 16; ++s) {
                float xv = xs[(srow * 16 + s) * 32 + hl];
                #pragma unroll
                for (int u = 0; u + s < 16; ++u) acc[s+u] += kr[u] * xv;
            }
        }
        #pragma unroll
        for (int j = 0; j < 16; ++j) {
            int p = i * 16 + j;
            float vv = acc[j] + xs[p * 32 + hl] * om;
            out[(size_t)p * 8192 + b * 256 + h0 + hl] = vv / (1.f + __expf(-vv));
        }
    }
}

extern "C" void kernel_launch(void* const* d_in, const int* in_sizes, int n_in,
                              void* d_out, int out_size, void* d_ws, size_t ws_size,
                              hipStream_t stream) {
    const float* x  = (const float*)d_in[0];
    const float* A1 = (const float*)d_in[1];
    const float* A2 = (const float*)d_in[2];
    const float* A3 = (const float*)d_in[3];
    const float* A4 = (const float*)d_in[4];
    const float* B1 = (const float*)d_in[5];
    const float* B2 = (const float*)d_in[6];
    const float* C1 = (const float*)d_in[7];
    const float* C2 = (const float*)d_in[8];
    const float* omega = (const float*)d_in[9];
    float* out = (float*)d_out;
    float* P   = (float*)d_ws;           // 32*256 floats = 32 KB partial d-sums
    hipLaunchKernelGGL(ssm_kP, dim3(8),   dim3(64),  0, stream,
                       A1, A2, A3, A4, B1, B2, P);
    hipLaunchKernelGGL(ssm_k3, dim3(256), dim3(256), 0, stream,
                       x, P, C1, C2, omega, out);
}